// Round 1
// baseline (5676.888 us; speedup 1.0000x reference)
//
#include <hip/hip_runtime.h>
#include <stdint.h>

typedef short s16x8 __attribute__((ext_vector_type(8)));
typedef float f32x4 __attribute__((ext_vector_type(4)));

#define LSEG 511
#define BT 16

static __device__ __forceinline__ unsigned short f2bf(float f) {
  union { float f; uint32_t u; } v; v.f = f;
  uint32_t r = (v.u + 0x7FFFu + ((v.u >> 16) & 1u)) >> 16;
  return (unsigned short)r;
}
static __device__ __forceinline__ float bf2f(unsigned short s) {
  union { uint32_t u; float f; } v; v.u = ((uint32_t)s) << 16;
  return v.f;
}
static __device__ __forceinline__ float tanh_fast(float x) {
  float ex = __expf(2.f * x);
  return 1.f - 2.f * __builtin_amdgcn_rcpf(ex + 1.f);
}

// One block = 16 batch rows, 4 waves. Weights live in per-wave register
// fragments (bf16) for the whole 511-step integration. Activations ping-pong
// between two padded LDS buffers. State (z, k1..k3) stays fp32 in LDS.
__global__ __launch_bounds__(256, 1) void cde_kernel(
    const float* __restrict__ coeffs,
    const float* __restrict__ W_init, const float* __restrict__ b_init,
    const float* __restrict__ W_in,  const float* __restrict__ b_in,
    const float* __restrict__ W_h,   const float* __restrict__ b_h,
    const float* __restrict__ W_out, const float* __restrict__ b_out,
    const float* __restrict__ W_read,const float* __restrict__ b_read,
    float* __restrict__ out)
{
  __shared__ unsigned short hb0[16][520];  // +8 pad: 1040B row stride
  __shared__ unsigned short hb1[16][520];
  __shared__ float zb[16][64];
  __shared__ float kb[3][16][64];
  __shared__ float dxb[16][8];
  __shared__ float cbuf[16][24];

  const int tid  = threadIdx.x;
  const int w    = tid >> 6;     // wave id 0..3
  const int lane = tid & 63;
  const int lr   = lane & 15;    // col within 16-wide tile / A row
  const int lk   = lane >> 4;    // k-subgroup 0..3
  const int b0   = blockIdx.x * BT;

  // ---- preload weight fragments (MFMA B-operand layout, bf16) ----
  // B-frag: elem e of lane = W[k = 32*kq + 8*lk + e][n = ncol0 + lr]
  s16x8 Win_f[2][2];
  s16x8 Wh0_f[4][2];
  s16x8 Wh1_f[4][2];
  s16x8 Wout_f[4][8];
  #pragma unroll
  for (int kq = 0; kq < 2; ++kq)
    #pragma unroll
    for (int nt = 0; nt < 2; ++nt) {
      const int ncol = 32*w + 16*nt + lr;
      #pragma unroll
      for (int e = 0; e < 8; ++e)
        Win_f[kq][nt][e] = (short)f2bf(W_in[(32*kq + 8*lk + e)*128 + ncol]);
    }
  #pragma unroll
  for (int kq = 0; kq < 4; ++kq)
    #pragma unroll
    for (int nt = 0; nt < 2; ++nt) {
      const int ncol = 32*w + 16*nt + lr;
      #pragma unroll
      for (int e = 0; e < 8; ++e) {
        Wh0_f[kq][nt][e] = (short)f2bf(W_h[(32*kq + 8*lk + e)*128 + ncol]);
        Wh1_f[kq][nt][e] = (short)f2bf(W_h[16384 + (32*kq + 8*lk + e)*128 + ncol]);
      }
    }
  #pragma unroll
  for (int kq = 0; kq < 4; ++kq)
    #pragma unroll
    for (int nt = 0; nt < 8; ++nt) {
      const int ncol = 128*w + 16*nt + lr;
      #pragma unroll
      for (int e = 0; e < 8; ++e)
        Wout_f[kq][nt][e] = (short)f2bf(W_out[(32*kq + 8*lk + e)*512 + ncol]);
    }
  float bin_t[2], bh0_t[2], bh1_t[2], bout_t[8];
  #pragma unroll
  for (int nt = 0; nt < 2; ++nt) {
    bin_t[nt] = b_in[32*w + 16*nt + lr];
    bh0_t[nt] = b_h[32*w + 16*nt + lr];
    bh1_t[nt] = b_h[128 + 32*w + 16*nt + lr];
  }
  #pragma unroll
  for (int nt = 0; nt < 8; ++nt)
    bout_t[nt] = b_out[128*w + 16*nt + lr];

  // ---- initial z = a[:,0,:] @ W_init + b_init ----
  {
    const int row = tid >> 4, hbase = (tid & 15) * 4;
    const float* a0 = &coeffs[(size_t)(b0 + row) * (LSEG * 32)];
    float a[8];
    #pragma unroll
    for (int c = 0; c < 8; ++c) a[c] = a0[c];
    #pragma unroll
    for (int j = 0; j < 4; ++j) {
      const int h = hbase + j;
      float s = b_init[h];
      #pragma unroll
      for (int c = 0; c < 8; ++c) s += a[c] * W_init[c*64 + h];
      zb[row][h] = s;
    }
  }
  __syncthreads();

  for (int t = 0; t < LSEG; ++t) {
    // stage segment coeffs: b, two_c, three_d (cols 8..31) for our 16 rows
    for (int i = tid; i < 384; i += 256) {
      const int row = i / 24, col = i - row*24;
      cbuf[row][col] = coeffs[((size_t)(b0+row)*LSEG + (size_t)t)*32 + 8 + col];
    }
    __syncthreads();

    #pragma unroll
    for (int s = 0; s < 4; ++s) {
      const float frac = (s==0) ? 0.f : (s==1) ? (1.f/3.f) : (s==2) ? (2.f/3.f) : 1.f;

      // phase 1: zz (bf16) -> hb0 ; dX -> dxb
      {
        const int row = tid >> 4, c0 = (tid & 15) * 4;
        f32x4 zv = *(const f32x4*)&zb[row][c0];
        if (s == 1) {
          f32x4 k1 = *(const f32x4*)&kb[0][row][c0];
          zv += (1.f/3.f)*k1;
        } else if (s == 2) {
          f32x4 k1 = *(const f32x4*)&kb[0][row][c0];
          f32x4 k2 = *(const f32x4*)&kb[1][row][c0];
          zv += k2 - (1.f/3.f)*k1;
        } else if (s == 3) {
          f32x4 k1 = *(const f32x4*)&kb[0][row][c0];
          f32x4 k2 = *(const f32x4*)&kb[1][row][c0];
          f32x4 k3 = *(const f32x4*)&kb[2][row][c0];
          zv += k1 - k2 + k3;
        }
        #pragma unroll
        for (int j = 0; j < 4; ++j) hb0[row][c0+j] = f2bf(zv[j]);
        if (tid < 128) {
          const int r2 = tid >> 3, c2 = tid & 7;
          const float bbv = cbuf[r2][c2], ccv = cbuf[r2][8+c2], ddv = cbuf[r2][16+c2];
          dxb[r2][c2] = bbv + (ccv + ddv*frac)*frac;
        }
      }
      __syncthreads();

      // layer 1: hb0(16x64) @ W_in + b_in, relu -> hb1(16x128)
      {
        s16x8 a[2];
        #pragma unroll
        for (int kq = 0; kq < 2; ++kq)
          a[kq] = *(const s16x8*)&hb0[lr][32*kq + 8*lk];
        f32x4 acc[2] = {};
        #pragma unroll
        for (int kq = 0; kq < 2; ++kq)
          #pragma unroll
          for (int nt = 0; nt < 2; ++nt)
            acc[nt] = __builtin_amdgcn_mfma_f32_16x16x32_bf16(a[kq], Win_f[kq][nt], acc[nt], 0, 0, 0);
        #pragma unroll
        for (int nt = 0; nt < 2; ++nt) {
          const int col = 32*w + 16*nt + lr;
          #pragma unroll
          for (int r = 0; r < 4; ++r)
            hb1[4*lk + r][col] = f2bf(fmaxf(acc[nt][r] + bin_t[nt], 0.f));
        }
      }
      __syncthreads();

      // layer 2: hb1(16x128) @ Wh0 + bh0, relu -> hb0(16x128)
      {
        s16x8 a[4];
        #pragma unroll
        for (int kq = 0; kq < 4; ++kq)
          a[kq] = *(const s16x8*)&hb1[lr][32*kq + 8*lk];
        f32x4 acc[2] = {};
        #pragma unroll
        for (int kq = 0; kq < 4; ++kq)
          #pragma unroll
          for (int nt = 0; nt < 2; ++nt)
            acc[nt] = __builtin_amdgcn_mfma_f32_16x16x32_bf16(a[kq], Wh0_f[kq][nt], acc[nt], 0, 0, 0);
        #pragma unroll
        for (int nt = 0; nt < 2; ++nt) {
          const int col = 32*w + 16*nt + lr;
          #pragma unroll
          for (int r = 0; r < 4; ++r)
            hb0[4*lk + r][col] = f2bf(fmaxf(acc[nt][r] + bh0_t[nt], 0.f));
        }
      }
      __syncthreads();

      // layer 3: hb0(16x128) @ Wh1 + bh1, relu -> hb1(16x128)
      {
        s16x8 a[4];
        #pragma unroll
        for (int kq = 0; kq < 4; ++kq)
          a[kq] = *(const s16x8*)&hb0[lr][32*kq + 8*lk];
        f32x4 acc[2] = {};
        #pragma unroll
        for (int kq = 0; kq < 4; ++kq)
          #pragma unroll
          for (int nt = 0; nt < 2; ++nt)
            acc[nt] = __builtin_amdgcn_mfma_f32_16x16x32_bf16(a[kq], Wh1_f[kq][nt], acc[nt], 0, 0, 0);
        #pragma unroll
        for (int nt = 0; nt < 2; ++nt) {
          const int col = 32*w + 16*nt + lr;
          #pragma unroll
          for (int r = 0; r < 4; ++r)
            hb1[4*lk + r][col] = f2bf(fmaxf(acc[nt][r] + bh1_t[nt], 0.f));
        }
      }
      __syncthreads();

      // layer 4: hb1(16x128) @ W_out + b_out, tanh -> hb0(16x512)
      {
        s16x8 a[4];
        #pragma unroll
        for (int kq = 0; kq < 4; ++kq)
          a[kq] = *(const s16x8*)&hb1[lr][32*kq + 8*lk];
        f32x4 acc[8] = {};
        #pragma unroll
        for (int kq = 0; kq < 4; ++kq)
          #pragma unroll
          for (int nt = 0; nt < 8; ++nt)
            acc[nt] = __builtin_amdgcn_mfma_f32_16x16x32_bf16(a[kq], Wout_f[kq][nt], acc[nt], 0, 0, 0);
        #pragma unroll
        for (int nt = 0; nt < 8; ++nt) {
          const int col = 128*w + 16*nt + lr;
          #pragma unroll
          for (int r = 0; r < 4; ++r)
            hb0[4*lk + r][col] = f2bf(tanh_fast(acc[nt][r] + bout_t[nt]));
        }
      }
      __syncthreads();

      // einsum: k_s[row][h] = sum_c f[row][h*8+c] * dX[row][c]
      {
        const int row = tid >> 4, hbase = (tid & 15) * 4;
        float dx[8];
        #pragma unroll
        for (int c = 0; c < 8; ++c) dx[c] = dxb[row][c];
        float kv[4];
        #pragma unroll
        for (int j = 0; j < 4; ++j) {
          const int h = hbase + j;
          s16x8 fv = *(const s16x8*)&hb0[row][h*8];
          float acc = 0.f;
          #pragma unroll
          for (int c = 0; c < 8; ++c) acc += bf2f((unsigned short)fv[c]) * dx[c];
          kv[j] = acc;
        }
        if (s < 3) {
          f32x4 kvv = { kv[0], kv[1], kv[2], kv[3] };
          *(f32x4*)&kb[s][row][hbase] = kvv;
        } else {
          f32x4 k1 = *(const f32x4*)&kb[0][row][hbase];
          f32x4 k2 = *(const f32x4*)&kb[1][row][hbase];
          f32x4 k3 = *(const f32x4*)&kb[2][row][hbase];
          f32x4 zv = *(const f32x4*)&zb[row][hbase];
          #pragma unroll
          for (int j = 0; j < 4; ++j)
            zv[j] += (k1[j] + 3.f*(k2[j] + k3[j]) + kv[j]) * 0.125f;
          *(f32x4*)&zb[row][hbase] = zv;
        }
      }
      __syncthreads();
    }
  }

  // readout: out[b] = z[b] @ W_read + b_read
  if (tid < BT) {
    float s = b_read[0];
    #pragma unroll
    for (int h = 0; h < 64; ++h) s += zb[tid][h] * W_read[h];
    out[b0 + tid] = s;
  }
}

extern "C" void kernel_launch(void* const* d_in, const int* in_sizes, int n_in,
                              void* d_out, int out_size, void* d_ws, size_t ws_size,
                              hipStream_t stream) {
  const float* coeffs = (const float*)d_in[0];
  const float* W_init = (const float*)d_in[1];
  const float* b_init = (const float*)d_in[2];
  const float* W_in   = (const float*)d_in[3];
  const float* b_in   = (const float*)d_in[4];
  const float* W_h    = (const float*)d_in[5];
  const float* b_h    = (const float*)d_in[6];
  const float* W_out  = (const float*)d_in[7];
  const float* b_out  = (const float*)d_in[8];
  const float* W_read = (const float*)d_in[9];
  const float* b_read = (const float*)d_in[10];
  float* out = (float*)d_out;

  cde_kernel<<<dim3(4096 / BT), dim3(256), 0, stream>>>(
      coeffs, W_init, b_init, W_in, b_in, W_h, b_h, W_out, b_out,
      W_read, b_read, out);
}